// Round 5
// baseline (1073.360 us; speedup 1.0000x reference)
//
#include <hip/hip_runtime.h>
#include <math.h>

// Problem constants
#define BB 2
#define TT 2048
#define CC 768
#define HH 12
#define NN 64
#define GG 2
#define CG 384   // C/G
#define FF 3145728L   // B*C*T
#define S1 1572864L   // B*384*T

typedef __attribute__((ext_vector_type(8))) short bf8frag;   // 8 bf16 (4 VGPRs)
typedef __attribute__((ext_vector_type(4))) float f4acc;     // 4 fp32 acc

__device__ inline unsigned short f2bf(float x) {
    union { float f; unsigned u; } v; v.f = x;
    unsigned r = v.u + 0x7FFFu + ((v.u >> 16) & 1u);   // RNE
    return (unsigned short)(r >> 16);
}
__device__ inline float bf2f(unsigned short u) {
    union { unsigned u; float f; } v; v.u = ((unsigned)u) << 16;
    return v.f;
}

// ---------------------------------------------------------------------------
// Generic fp32 tiled GEMM v1: 64x64 tile, 256 threads, 4x4 micro-tile.
// bfout: optional bf16 side-write (mix GEMM emits bf16 xr/xk/xv copies).
// MODE==2: fp32 store skipped for zi in {0,3} (xr/xv fp32 never read).
// ---------------------------------------------------------------------------
template<int ATRANS, int BTRANS, int TOUT, int MODE>
__global__ __launch_bounds__(256) void gemm_kernel(
    const float* __restrict__ A, const float* __restrict__ Bm, float* __restrict__ Cm,
    const float* __restrict__ aux, const float* __restrict__ aux2,
    int K, int ldA, int ldB, int ldC, int zInner,
    long sA_o, long sA_i, long sB_o, long sB_i, long sC_o, long sC_i,
    long sAux_i, long sAux2_o, unsigned short* bfout)
{
    const int zo = blockIdx.z / zInner;
    const int zi = blockIdx.z % zInner;
    A  += (size_t)zo * sA_o + (size_t)zi * sA_i;
    Bm += (size_t)zo * sB_o + (size_t)zi * sB_i;
    Cm += (size_t)zo * sC_o + (size_t)zi * sC_i;
    if (MODE == 2) { aux += (size_t)zi * sAux_i; aux2 += (size_t)zo * sAux2_o; }

    const int m0t = blockIdx.y * 64;
    const int n0t = blockIdx.x * 64;
    const int tid = threadIdx.x;

    __shared__ float As[16][64];
    __shared__ float Bs[16][64];

    int mi, ni;
    if (TOUT) { mi = (tid & 15) * 4; ni = (tid >> 4) * 4; }
    else      { ni = (tid & 15) * 4; mi = (tid >> 4) * 4; }

    float acc[4][4];
#pragma unroll
    for (int i = 0; i < 4; ++i)
#pragma unroll
        for (int j = 0; j < 4; ++j) acc[i][j] = 0.f;

    for (int k0 = 0; k0 < K; k0 += 16) {
        if (!ATRANS) {
            const int row = tid >> 2;
            const int kc  = (tid & 3) * 4;
            float4 av = *(const float4*)&A[(size_t)(m0t + row) * ldA + k0 + kc];
            As[kc + 0][row] = av.x; As[kc + 1][row] = av.y;
            As[kc + 2][row] = av.z; As[kc + 3][row] = av.w;
        } else {
            const int krow = tid >> 4;
            const int mc   = (tid & 15) * 4;
            *(float4*)&As[krow][mc] = *(const float4*)&A[(size_t)(k0 + krow) * ldA + m0t + mc];
        }
        if (!BTRANS) {
            const int krow = tid >> 4;
            const int tc   = (tid & 15) * 4;
            *(float4*)&Bs[krow][tc] = *(const float4*)&Bm[(size_t)(k0 + krow) * ldB + n0t + tc];
        } else {
            const int trow = tid >> 2;
            const int kc   = (tid & 3) * 4;
            float4 bv = *(const float4*)&Bm[(size_t)(n0t + trow) * ldB + k0 + kc];
            Bs[kc + 0][trow] = bv.x; Bs[kc + 1][trow] = bv.y;
            Bs[kc + 2][trow] = bv.z; Bs[kc + 3][trow] = bv.w;
        }
        __syncthreads();
#pragma unroll
        for (int kk = 0; kk < 16; ++kk) {
            float4 a4 = *(const float4*)&As[kk][mi];
            float4 b4 = *(const float4*)&Bs[kk][ni];
            float am[4] = {a4.x, a4.y, a4.z, a4.w};
            float bn[4] = {b4.x, b4.y, b4.z, b4.w};
#pragma unroll
            for (int i = 0; i < 4; ++i)
#pragma unroll
                for (int j = 0; j < 4; ++j) acc[i][j] = fmaf(am[i], bn[j], acc[i][j]);
        }
        __syncthreads();
    }

    const int mbase = m0t + mi, nbase = n0t + ni;
#pragma unroll
    for (int i = 0; i < 4; ++i) {
        float4 xv;
        if (MODE == 2) xv = *(const float4*)&aux2[(size_t)(mbase + i) * ldC + nbase];
        float xa[4] = {0.f, 0.f, 0.f, 0.f};
        if (MODE == 2) { xa[0] = xv.x; xa[1] = xv.y; xa[2] = xv.z; xa[3] = xv.w; }
#pragma unroll
        for (int j = 0; j < 4; ++j) {
            float v = acc[i][j];
            if (MODE == 1) v = tanhf(v);
            else if (MODE == 2) v = xa[j] * (aux[mbase + i] + v);
            else if (MODE == 3) {
                float u  = aux[mbase + i] + v;
                float sp = fmaxf(-u, 0.f) + log1pf(expf(-fabsf(u)));  // softplus(-u)
                float wl = -sp - 0.5f;
                v = expf(-expf(wl));
            } else if (MODE == 4) {
                float u = aux[mbase + i] + v;
                v = 1.f / (1.f + expf(-u));
            }
            acc[i][j] = v;
        }
    }
    if (!TOUT) {
        const bool skipf = (MODE == 2) && (bfout != nullptr) && (zi == 0 || zi == 3);
        if (!skipf) {
#pragma unroll
            for (int i = 0; i < 4; ++i) {
                float4 o = {acc[i][0], acc[i][1], acc[i][2], acc[i][3]};
                *(float4*)&Cm[(size_t)(mbase + i) * ldC + nbase] = o;
            }
        }
        // bf16 side-write for MFMA conv inputs: slots n in {0:xr, 2:xk, 3:xv}
        if (MODE == 2 && bfout != nullptr) {
            int sidx = (zi == 0) ? 0 : (zi == 2) ? 1 : (zi == 3) ? 2 : -1;
            if (sidx >= 0) {
                unsigned short* bp = bfout + (size_t)sidx * FF + (size_t)zo * ((long)CC * TT);
#pragma unroll
                for (int i = 0; i < 4; ++i) {
                    ushort4 o = {f2bf(acc[i][0]), f2bf(acc[i][1]), f2bf(acc[i][2]), f2bf(acc[i][3])};
                    *(ushort4*)&bp[(size_t)(mbase + i) * ldC + nbase] = o;
                }
            }
        }
    } else {
#pragma unroll
        for (int j = 0; j < 4; ++j) {
            float4 o = {acc[0][j], acc[1][j], acc[2][j], acc[3][j]};
            *(float4*)&Cm[(size_t)(nbase + j) * ldC + mbase] = o;
        }
    }
}

// ---------------------------------------------------------------------------
// Merged lora-hidden GEMMs (decay/aaa/kkk/gate _w1): tanh(W @ x_slot).
// grid (32,3,8): z = which*2 + b; which<3 uses only blockIdx.y==0 (M=64).
// ---------------------------------------------------------------------------
__global__ __launch_bounds__(256) void lorah_kernel(
    const float* __restrict__ w0, const float* __restrict__ w1,
    const float* __restrict__ w2, const float* __restrict__ w3,
    const float* __restrict__ x0, const float* __restrict__ x1,
    const float* __restrict__ x2, const float* __restrict__ x3,
    float* __restrict__ o0, float* __restrict__ o1,
    float* __restrict__ o2, float* __restrict__ o3)
{
    const int z = blockIdx.z;
    const int which = z >> 1, bz = z & 1;
    if (which < 3 && blockIdx.y > 0) return;
    const float* A; const float* Bm; float* Cm; int M;
    if (which == 0)      { A = w0; Bm = x0; Cm = o0; M = 64; }
    else if (which == 1) { A = w1; Bm = x1; Cm = o1; M = 64; }
    else if (which == 2) { A = w2; Bm = x2; Cm = o2; M = 64; }
    else                 { A = w3; Bm = x3; Cm = o3; M = 192; }
    Bm += (size_t)bz * ((long)CC * TT);
    Cm += (size_t)bz * ((long)M * TT);

    const int m0t = blockIdx.y * 64;
    const int n0t = blockIdx.x * 64;
    const int tid = threadIdx.x;

    __shared__ float As[16][64];
    __shared__ float Bs[16][64];

    const int ni = (tid & 15) * 4, mi = (tid >> 4) * 4;
    float acc[4][4];
#pragma unroll
    for (int i = 0; i < 4; ++i)
#pragma unroll
        for (int j = 0; j < 4; ++j) acc[i][j] = 0.f;

    for (int k0 = 0; k0 < CC; k0 += 16) {
        {
            const int row = tid >> 2, kc = (tid & 3) * 4;
            float4 av = *(const float4*)&A[(size_t)(m0t + row) * CC + k0 + kc];
            As[kc + 0][row] = av.x; As[kc + 1][row] = av.y;
            As[kc + 2][row] = av.z; As[kc + 3][row] = av.w;
        }
        {
            const int krow = tid >> 4, tc = (tid & 15) * 4;
            *(float4*)&Bs[krow][tc] = *(const float4*)&Bm[(size_t)(k0 + krow) * TT + n0t + tc];
        }
        __syncthreads();
#pragma unroll
        for (int kk = 0; kk < 16; ++kk) {
            float4 a4 = *(const float4*)&As[kk][mi];
            float4 b4 = *(const float4*)&Bs[kk][ni];
            float am[4] = {a4.x, a4.y, a4.z, a4.w};
            float bn[4] = {b4.x, b4.y, b4.z, b4.w};
#pragma unroll
            for (int i = 0; i < 4; ++i)
#pragma unroll
                for (int j = 0; j < 4; ++j) acc[i][j] = fmaf(am[i], bn[j], acc[i][j]);
        }
        __syncthreads();
    }
    const int mbase = m0t + mi, nbase = n0t + ni;
#pragma unroll
    for (int i = 0; i < 4; ++i) {
        float4 o = {tanhf(acc[i][0]), tanhf(acc[i][1]), tanhf(acc[i][2]), tanhf(acc[i][3])};
        *(float4*)&Cm[(size_t)(mbase + i) * TT + nbase] = o;
    }
}

// ---------------------------------------------------------------------------
// Merged lora-out GEMMs (decay/aaa/kkk _w2): one launch, runtime epilogue.
// grid (32,12,6): z = which*2 + b. K=64 for all three; TOUT layout.
//   which 0: ww = exp(-exp(-softplus(-(tdecay + v)) - 0.5))
//   which 1: b2-slot = sigmoid(taaaaa + v)
//   which 2: kvec (raw)
// ---------------------------------------------------------------------------
__global__ __launch_bounds__(256) void loraout_kernel(
    const float* __restrict__ dw2, const float* __restrict__ aw2,
    const float* __restrict__ kw2,
    const float* __restrict__ dhh, const float* __restrict__ ahh,
    const float* __restrict__ khh,
    const float* __restrict__ tdecay, const float* __restrict__ taaaaa,
    float* __restrict__ wwB, float* __restrict__ b2B, float* __restrict__ aaB)
{
    const int z = blockIdx.z;
    const int which = z >> 1, bz = z & 1;
    const float* A; const float* Bm; float* Cm; const float* aux;
    if (which == 0)      { A = dw2; Bm = dhh; Cm = wwB; aux = tdecay; }
    else if (which == 1) { A = aw2; Bm = ahh; Cm = b2B; aux = taaaaa; }
    else                 { A = kw2; Bm = khh; Cm = aaB; aux = nullptr; }
    Bm += (size_t)bz * (64L * TT);
    Cm += (size_t)bz * ((long)TT * CC);

    const int m0t = blockIdx.y * 64;
    const int n0t = blockIdx.x * 64;
    const int tid = threadIdx.x;

    __shared__ float As[16][64];
    __shared__ float Bs[16][64];

    const int mi = (tid & 15) * 4, ni = (tid >> 4) * 4;   // TOUT layout
    float acc[4][4];
#pragma unroll
    for (int i = 0; i < 4; ++i)
#pragma unroll
        for (int j = 0; j < 4; ++j) acc[i][j] = 0.f;

    for (int k0 = 0; k0 < 64; k0 += 16) {
        {
            const int row = tid >> 2, kc = (tid & 3) * 4;
            float4 av = *(const float4*)&A[(size_t)(m0t + row) * 64 + k0 + kc];
            As[kc + 0][row] = av.x; As[kc + 1][row] = av.y;
            As[kc + 2][row] = av.z; As[kc + 3][row] = av.w;
        }
        {
            const int krow = tid >> 4, tc = (tid & 15) * 4;
            *(float4*)&Bs[krow][tc] = *(const float4*)&Bm[(size_t)(k0 + krow) * TT + n0t + tc];
        }
        __syncthreads();
#pragma unroll
        for (int kk = 0; kk < 16; ++kk) {
            float4 a4 = *(const float4*)&As[kk][mi];
            float4 b4 = *(const float4*)&Bs[kk][ni];
            float am[4] = {a4.x, a4.y, a4.z, a4.w};
            float bn[4] = {b4.x, b4.y, b4.z, b4.w};
#pragma unroll
            for (int i = 0; i < 4; ++i)
#pragma unroll
                for (int j = 0; j < 4; ++j) acc[i][j] = fmaf(am[i], bn[j], acc[i][j]);
        }
        __syncthreads();
    }
    const int mbase = m0t + mi, nbase = n0t + ni;
#pragma unroll
    for (int i = 0; i < 4; ++i) {
#pragma unroll
        for (int j = 0; j < 4; ++j) {
            float v = acc[i][j];
            if (which == 0) {
                float u  = aux[mbase + i] + v;
                float sp = fmaxf(-u, 0.f) + log1pf(expf(-fabsf(u)));  // softplus(-u)
                v = expf(-expf(-sp - 0.5f));
            } else if (which == 1) {
                float u = aux[mbase + i] + v;
                v = 1.f / (1.f + expf(-u));
            }
            acc[i][j] = v;
        }
    }
#pragma unroll
    for (int j = 0; j < 4; ++j) {
        float4 o = {acc[0][j], acc[1][j], acc[2][j], acc[3][j]};
        *(float4*)&Cm[(size_t)(nbase + j) * CC + mbase] = o;
    }
}

// ---------------------------------------------------------------------------
// Merged 3 input convs via bf16 MFMA: grid (16,3,12), z = conv*4 + b*2 + g.
// ---------------------------------------------------------------------------
__global__ __launch_bounds__(256) void convs3_mfma_kernel(
    const unsigned short* __restrict__ wball, const unsigned short* __restrict__ X6t,
    float* __restrict__ X6)
{
    const int z = blockIdx.z;
    const int conv = z >> 2, bg = z & 3, b = bg >> 1, g = bg & 1;
    const unsigned short* Wb = wball + (size_t)conv * 294912;
    const unsigned short* Xb = X6t + (size_t)conv * FF;
    const int oslot = (conv == 0) ? 1 : (conv == 1) ? 4 : 5;
    float* Cout = X6 + (size_t)oslot * FF;

    const int t0 = blockIdx.x * 128;
    const int m0 = blockIdx.y * 128;
    const int tid = threadIdx.x;
    const int wave = tid >> 6, lane = tid & 63;
    const int lq = lane >> 4, lr = lane & 15;

    __shared__ unsigned short Ws[128 * 40];
    __shared__ unsigned short Xs[128 * 40];

    const unsigned short* Wg = Wb + (size_t)g * (CG * CG);
    const long xbase = (long)b * (long)TT * CC;

    f4acc acc0[8], acc1[8];
#pragma unroll
    for (int j = 0; j < 8; ++j) { acc0[j] = (f4acc)0.f; acc1[j] = (f4acc)0.f; }

    for (int k0 = 0; k0 < CG; k0 += 32) {
        {
            const int m = tid >> 1, kc = (tid & 1) * 16;
            const unsigned short* src = Wg + (size_t)(m0 + m) * CG + k0 + kc;
            *(bf8frag*)&Ws[m * 40 + kc]     = *(const bf8frag*)src;
            *(bf8frag*)&Ws[m * 40 + kc + 8] = *(const bf8frag*)(src + 8);
        }
        {
            const int t = tid >> 1, kc = (tid & 1) * 16;
            const unsigned short* src = Xb + xbase + (long)(t0 + t) * CC + g * CG + k0 + kc;
            *(bf8frag*)&Xs[t * 40 + kc]     = *(const bf8frag*)src;
            *(bf8frag*)&Xs[t * 40 + kc + 8] = *(const bf8frag*)(src + 8);
        }
        __syncthreads();

        bf8frag a0 = *(const bf8frag*)&Ws[(32 * wave + lr) * 40 + lq * 8];
        bf8frag a1 = *(const bf8frag*)&Ws[(32 * wave + 16 + lr) * 40 + lq * 8];
#pragma unroll
        for (int nj = 0; nj < 8; ++nj) {
            bf8frag bb = *(const bf8frag*)&Xs[(16 * nj + lr) * 40 + lq * 8];
            acc0[nj] = __builtin_amdgcn_mfma_f32_16x16x32_bf16(a0, bb, acc0[nj], 0, 0, 0);
            acc1[nj] = __builtin_amdgcn_mfma_f32_16x16x32_bf16(a1, bb, acc1[nj], 0, 0, 0);
        }
        __syncthreads();
    }

#pragma unroll
    for (int fi = 0; fi < 2; ++fi) {
        const int cbase = m0 + 32 * wave + 16 * fi + lq * 4;
#pragma unroll
        for (int nj = 0; nj < 8; ++nj) {
            const f4acc av = fi ? acc1[nj] : acc0[nj];
            const int t = t0 + 16 * nj + lr;
            float4 o = {av[0], av[1], av[2], av[3]};
            *(float4*)&Cout[(long)b * (long)TT * CC + (long)t * CC + g * CG + cbase] = o;
        }
    }
}

// ---------------------------------------------------------------------------
// Output conv via bf16 MFMA: z (B,T,C) bf16 -> out (B,C,T) fp32.
// ---------------------------------------------------------------------------
__global__ __launch_bounds__(256) void convout_mfma_kernel(
    const unsigned short* __restrict__ Wb, const unsigned short* __restrict__ Xb,
    float* __restrict__ Cout)
{
    const int bz = blockIdx.z; const int b = bz >> 1, g = bz & 1;
    const int t0 = blockIdx.x * 128;
    const int m0 = blockIdx.y * 128;
    const int tid = threadIdx.x;
    const int wave = tid >> 6, lane = tid & 63;
    const int lq = lane >> 4, lr = lane & 15;

    __shared__ unsigned short Ws[128 * 40];
    __shared__ unsigned short Xs[128 * 40];

    const unsigned short* Wg = Wb + (size_t)g * (CG * CG);
    const long xbase = (long)b * (long)TT * CC;

    f4acc acc0[8], acc1[8];
#pragma unroll
    for (int j = 0; j < 8; ++j) { acc0[j] = (f4acc)0.f; acc1[j] = (f4acc)0.f; }

    for (int k0 = 0; k0 < CG; k0 += 32) {
        {
            const int m = tid >> 1, kc = (tid & 1) * 16;
            const unsigned short* src = Wg + (size_t)(m0 + m) * CG + k0 + kc;
            *(bf8frag*)&Ws[m * 40 + kc]     = *(const bf8frag*)src;
            *(bf8frag*)&Ws[m * 40 + kc + 8] = *(const bf8frag*)(src + 8);
        }
        {
            const int t = tid >> 1, kc = (tid & 1) * 16;
            const unsigned short* src = Xb + xbase + (long)(t0 + t) * CC + g * CG + k0 + kc;
            *(bf8frag*)&Xs[t * 40 + kc]     = *(const bf8frag*)src;
            *(bf8frag*)&Xs[t * 40 + kc + 8] = *(const bf8frag*)(src + 8);
        }
        __syncthreads();

        bf8frag a0 = *(const bf8frag*)&Ws[(32 * wave + lr) * 40 + lq * 8];
        bf8frag a1 = *(const bf8frag*)&Ws[(32 * wave + 16 + lr) * 40 + lq * 8];
#pragma unroll
        for (int nj = 0; nj < 8; ++nj) {
            bf8frag bb = *(const bf8frag*)&Xs[(16 * nj + lr) * 40 + lq * 8];
            acc0[nj] = __builtin_amdgcn_mfma_f32_16x16x32_bf16(a0, bb, acc0[nj], 0, 0, 0);
            acc1[nj] = __builtin_amdgcn_mfma_f32_16x16x32_bf16(a1, bb, acc1[nj], 0, 0, 0);
        }
        __syncthreads();
    }

#pragma unroll
    for (int fi = 0; fi < 2; ++fi) {
        const int cbase = m0 + 32 * wave + 16 * fi + lq * 4;
#pragma unroll
        for (int nj = 0; nj < 8; ++nj) {
            const f4acc av = fi ? acc1[nj] : acc0[nj];
            const int t = t0 + 16 * nj + lr;
#pragma unroll
            for (int i = 0; i < 4; ++i)
                Cout[(long)b * (long)CC * TT + (long)(g * CG + cbase + i) * TT + t] = av[i];
        }
    }
}

// ---------------------------------------------------------------------------
// maa_w1 bf16 MFMA GEMM: tm(b,384,T) = tanh( W(384x768) @ x(b,768,T) ).
// ---------------------------------------------------------------------------
__global__ __launch_bounds__(256) void maaw1_mfma_kernel(
    const unsigned short* __restrict__ Wb, const unsigned short* __restrict__ Xb,
    float* __restrict__ Cout)
{
    const int b = blockIdx.z;
    const int t0 = blockIdx.x * 128;
    const int m0 = blockIdx.y * 128;
    const int tid = threadIdx.x;
    const int wave = tid >> 6, lane = tid & 63;
    const int lq = lane >> 4, lr = lane & 15;

    __shared__ unsigned short Ws[128 * 40];
    __shared__ unsigned short Xs[128 * 40];

    const long xbase = (long)b * (long)TT * CC;

    f4acc acc0[8], acc1[8];
#pragma unroll
    for (int j = 0; j < 8; ++j) { acc0[j] = (f4acc)0.f; acc1[j] = (f4acc)0.f; }

    for (int k0 = 0; k0 < CC; k0 += 32) {
        {
            const int m = tid >> 1, kc = (tid & 1) * 16;
            const unsigned short* src = Wb + (size_t)(m0 + m) * CC + k0 + kc;
            *(bf8frag*)&Ws[m * 40 + kc]     = *(const bf8frag*)src;
            *(bf8frag*)&Ws[m * 40 + kc + 8] = *(const bf8frag*)(src + 8);
        }
        {
            const int t = tid >> 1, kc = (tid & 1) * 16;
            const unsigned short* src = Xb + xbase + (long)(t0 + t) * CC + k0 + kc;
            *(bf8frag*)&Xs[t * 40 + kc]     = *(const bf8frag*)src;
            *(bf8frag*)&Xs[t * 40 + kc + 8] = *(const bf8frag*)(src + 8);
        }
        __syncthreads();

        bf8frag a0 = *(const bf8frag*)&Ws[(32 * wave + lr) * 40 + lq * 8];
        bf8frag a1 = *(const bf8frag*)&Ws[(32 * wave + 16 + lr) * 40 + lq * 8];
#pragma unroll
        for (int nj = 0; nj < 8; ++nj) {
            bf8frag bb = *(const bf8frag*)&Xs[(16 * nj + lr) * 40 + lq * 8];
            acc0[nj] = __builtin_amdgcn_mfma_f32_16x16x32_bf16(a0, bb, acc0[nj], 0, 0, 0);
            acc1[nj] = __builtin_amdgcn_mfma_f32_16x16x32_bf16(a1, bb, acc1[nj], 0, 0, 0);
        }
        __syncthreads();
    }

#pragma unroll
    for (int fi = 0; fi < 2; ++fi) {
        const int m = m0 + 32 * wave + 16 * fi + lq * 4;
#pragma unroll
        for (int nj = 0; nj < 8; ++nj) {
            const f4acc av = fi ? acc1[nj] : acc0[nj];
            const int t = t0 + 16 * nj + lr;
#pragma unroll
            for (int i = 0; i < 4; ++i)
                Cout[(long)b * 384 * TT + (long)(m + i) * TT + t] = tanhf(av[i]);
        }
    }
}

// ---------------------------------------------------------------------------
// Transpose kernels (LDS 64x64 tiles)
// ---------------------------------------------------------------------------
__global__ __launch_bounds__(256) void xtr_kernel(const float* __restrict__ xin,
                                                  unsigned short* __restrict__ xout)
{
    __shared__ unsigned short L[64][68];
    const int t0 = blockIdx.x * 64, c0 = blockIdx.y * 64, b = blockIdx.z;
    const int tid = threadIdx.x;
    const int lr = tid >> 4, lc = (tid & 15) * 4;
#pragma unroll
    for (int i = 0; i < 4; ++i) {
        int c = lr + i * 16;
        float4 v = *(const float4*)&xin[(size_t)b * CC * TT + (size_t)(c0 + c) * TT + t0 + lc];
        L[c][lc + 0] = f2bf(v.x); L[c][lc + 1] = f2bf(v.y);
        L[c][lc + 2] = f2bf(v.z); L[c][lc + 3] = f2bf(v.w);
    }
    __syncthreads();
#pragma unroll
    for (int i = 0; i < 4; ++i) {
        int t = lr + i * 16;
        ushort4 o = {L[lc + 0][t], L[lc + 1][t], L[lc + 2][t], L[lc + 3][t]};
        *(ushort4*)&xout[(size_t)b * TT * CC + (size_t)(t0 + t) * CC + c0 + lc] = o;
    }
}

__global__ __launch_bounds__(256) void btr_kernel(const unsigned short* __restrict__ xin,
                                                  unsigned short* __restrict__ xout)
{
    __shared__ unsigned short L[64][68];
    const int t0 = blockIdx.x * 64, c0 = blockIdx.y * 64;
    const int s = blockIdx.z >> 1, b = blockIdx.z & 1;
    const int tid = threadIdx.x;
    const int lr = tid >> 4, lc = (tid & 15) * 4;
    const size_t ibase = (size_t)s * FF + (size_t)b * CC * TT;
    const size_t obase = (size_t)s * FF + (size_t)b * TT * CC;
#pragma unroll
    for (int i = 0; i < 4; ++i) {
        int c = lr + i * 16;
        ushort4 v = *(const ushort4*)&xin[ibase + (size_t)(c0 + c) * TT + t0 + lc];
        L[c][lc + 0] = v.x; L[c][lc + 1] = v.y; L[c][lc + 2] = v.z; L[c][lc + 3] = v.w;
    }
    __syncthreads();
#pragma unroll
    for (int i = 0; i < 4; ++i) {
        int t = lr + i * 16;
        ushort4 o = {L[lc + 0][t], L[lc + 1][t], L[lc + 2][t], L[lc + 3][t]};
        *(ushort4*)&xout[obase + (size_t)(t0 + t) * CC + c0 + lc] = o;
    }
}

// ---------------------------------------------------------------------------
// wcvt + pack_aux merged (block 5760 does pack_aux; 0..5759 do wcvt)
// ---------------------------------------------------------------------------
__global__ void wcvt_kernel(const float* __restrict__ w0, const float* __restrict__ w1,
                            const float* __restrict__ w2, const float* __restrict__ w3,
                            const float* __restrict__ w4, unsigned short* __restrict__ wb,
                            const float* __restrict__ pr, const float* __restrict__ pw,
                            const float* __restrict__ pk, const float* __restrict__ pv,
                            const float* __restrict__ pa, const float* __restrict__ pg,
                            float* __restrict__ paux)
{
    if (blockIdx.x == 5760) {
#pragma unroll
        for (int ch = 0; ch < 3; ++ch) {
            int c = ch * 256 + threadIdx.x;
            paux[0 * CC + c] = 1.f + pr[c];
            paux[1 * CC + c] = 1.f + pw[c];
            paux[2 * CC + c] = 1.f + pk[c];
            paux[3 * CC + c] = 1.f + pv[c];
            paux[4 * CC + c] = 1.f + pa[c];
            paux[5 * CC + c] = 1.f + pg[c];
        }
        return;
    }
    const int i = blockIdx.x * 256 + threadIdx.x;   // total 5*294912
    const int which = i / 294912, r = i - which * 294912;
    const float* s = (which == 0) ? w0 : (which == 1) ? w1 : (which == 2) ? w2
                   : (which == 3) ? w3 : w4;
    wb[i] = f2bf(s[r]);
}

// ---------------------------------------------------------------------------
// E1: per token, kk = k + kvec; per-head L2-normalize; aa=-kkn, b2=kkn*a.
// ---------------------------------------------------------------------------
__global__ __launch_bounds__(256) void e1_kernel(const float* __restrict__ kA,
                                                 float* __restrict__ kvecA,
                                                 float* __restrict__ aA)
{
    const size_t base = (size_t)blockIdx.x * CC;
    const int tid = threadIdx.x;
#pragma unroll
    for (int ch = 0; ch < 3; ++ch) {
        int c = ch * 256 + tid;
        float kk = kA[base + c] + kvecA[base + c];
        float ss = kk * kk;
#pragma unroll
        for (int off = 32; off; off >>= 1) ss += __shfl_xor(ss, off, 64);
        float denom = fmaxf(sqrtf(ss), 1e-12f);
        float kkn = kk / denom;
        float av = aA[base + c];
        kvecA[base + c] = -kkn;       // aa
        aA[base + c]    = kkn * av;   // b2
    }
}

// ---------------------------------------------------------------------------
// BG: per (b,h,t): beta_t = b2_{t-1}.aa_t ; gamma_t = k_{t-1}.aa_t
// One block per (b,t), 256 threads; each wave covers exactly one head.
// ---------------------------------------------------------------------------
__global__ __launch_bounds__(256) void bg_kernel(
    const float* __restrict__ b2A, const float* __restrict__ aaA,
    const float* __restrict__ kA, float2* __restrict__ bgout)
{
    const int bt = blockIdx.x;           // b*TT + t
    const int b = bt / TT, t = bt - b * TT;
    const int tid = threadIdx.x;
    const size_t base  = (size_t)bt * CC;
    const size_t basep = base - CC;      // token t-1
#pragma unroll
    for (int ch = 0; ch < 3; ++ch) {
        int c = ch * 256 + tid;
        int h = c >> 6;
        float pb = 0.f, pk = 0.f;
        if (t > 0) {
            float av = aaA[base + c];
            pb = b2A[basep + c] * av;
            pk = kA[basep + c] * av;
        }
#pragma unroll
        for (int off = 32; off; off >>= 1) {
            pb += __shfl_xor(pb, off, 64);
            pk += __shfl_xor(pk, off, 64);
        }
        if ((tid & 63) == 0) {
            float2 o; o.x = pb; o.y = pk;
            bgout[(size_t)(b * HH + h) * TT + t] = o;
        }
    }
}

// ---------------------------------------------------------------------------
// WKV-7 v16: R=4 rows/wave (rg in [0,16), 384 wkv blocks) + beta/gamma
// pipelined tmp + 4-frag rotation. Per-lane frag = one float4 per array
// (23 floats) -> 4-frag rotation ~115 live values: FITS the register file
// (v13's 172 forced demotion -> loads sank onto the serial chain).
//   tmp_t = u_t + beta_t*tmp_{t-1} + gamma_t*v_{t-1}[row]
//   u_t   = sum_j S_{t-2}[j] w_{t-1}[j] a_t[j]  (flat-15 shuffle, off-chain)
// y partials pair-combined across jg^8 (xor 32) -> same 8 planes; e2 unchanged.
// Gate lora-out GEMM fused as blocks 384..1151 (runs in wkv latency shadow).
// NOTE: state scalars named Sa0..Sa3 (S1 is a macro!).
// ---------------------------------------------------------------------------
struct WFrag4 {
    float4 a, w, b, k, r;
    float vv, beta, gamma;
};

__global__ __launch_bounds__(256, 1) void wkv_gate_kernel(
    const float* __restrict__ rA, const float* __restrict__ wA,
    const float* __restrict__ kA, const float* __restrict__ vA,
    const float* __restrict__ aaA, const float* __restrict__ b2A,
    const float2* __restrict__ bgA,
    unsigned short* __restrict__ yp8,
    const float* __restrict__ gw2, const float* __restrict__ ghh,
    float* __restrict__ gbuf)
{
    if (blockIdx.x < 384) {
        // ---------------- wkv path ----------------
        if (threadIdx.x >= 64) return;
        const int blk = blockIdx.x;          // rg*24 + bh (all rg of a bh on one XCD)
        const int bh = blk % 24, rg = blk / 24;
        const int b = bh / HH, h = bh - b * HH;
        const int lane = threadIdx.x;
        const int jg = lane >> 2, p = lane & 3;   // 16 col groups x 4 rows
        const int row = rg * 4 + p;
        const int base = b * TT * CC + h * NN;
        const int fo = jg * 4;
        const int ybase = ((jg & 7) * BB + b) * (TT * CC) + h * NN + row;
        const float2* bgp = bgA + (size_t)bh * TT;

        float Sa0 = 0.f, Sa1 = 0.f, Sa2 = 0.f, Sa3 = 0.f;
        float tmp_prev = 0.f, v_prev = 0.f, u_cur = 0.f;

        WFrag4 f0, f1, f2, f3;

        auto loadfrag = [&](WFrag4& f, int t) {
            const int o = base + t * CC + fo;
            float2 bg2 = bgp[t];
            f.beta = bg2.x; f.gamma = bg2.y;
            f.a = *(const float4*)&aaA[o];
            f.w = *(const float4*)&wA[o];
            f.b = *(const float4*)&b2A[o];
            f.k = *(const float4*)&kA[o];
            f.r = *(const float4*)&rA[o];
            f.vv = vA[base + t * CC + row];
        };

        // f = frag for step t; fn = frag for t+1 (supplies a_{t+1})
        auto stepf = [&](const WFrag4& f, const WFrag4& fn, int t) {
            // serial chain: 2 dependent fmafs
            const float tmp = fmaf(f.beta, tmp_prev, fmaf(f.gamma, v_prev, u_cur));
            const float vv = f.vv;

            // u_{t+1} partials on OLD S (= S_{t-1}): S * (w_t ⊙ a_{t+1})
            float u0 = Sa0 * (f.w.x * fn.a.x);
            float u1 = Sa1 * (f.w.y * fn.a.y);
            float u2 = Sa2 * (f.w.z * fn.a.z);
            float u3 = Sa3 * (f.w.w * fn.a.w);
            const float upart = (u0 + u1) + (u2 + u3);
            // flat 15-shuffle reduce over the 16 col groups (depth 1, off-chain)
            float x01 = __shfl_xor(upart,  4, 64);
            float x02 = __shfl_xor(upart,  8, 64);
            float x03 = __shfl_xor(upart, 12, 64);
            float x04 = __shfl_xor(upart, 16, 64);
            float x05 = __shfl_xor(upart, 20, 64);
            float x06 = __shfl_xor(upart, 24, 64);
            float x07 = __shfl_xor(upart, 28, 64);
            float x08 = __shfl_xor(upart, 32, 64);
            float x09 = __shfl_xor(upart, 36, 64);
            float x10 = __shfl_xor(upart, 40, 64);
            float x11 = __shfl_xor(upart, 44, 64);
            float x12 = __shfl_xor(upart, 48, 64);
            float x13 = __shfl_xor(upart, 52, 64);
            float x14 = __shfl_xor(upart, 56, 64);
            float x15 = __shfl_xor(upart, 60, 64);

            // S update + y partial (chain: 1 fmaf per element)
            float y0, y1, y2, y3;
            Sa0 = fmaf(Sa0, f.w.x, fmaf(tmp, f.b.x, vv * f.k.x)); y0 = Sa0 * f.r.x;
            Sa1 = fmaf(Sa1, f.w.y, fmaf(tmp, f.b.y, vv * f.k.y)); y1 = Sa1 * f.r.y;
            Sa2 = fmaf(Sa2, f.w.z, fmaf(tmp, f.b.z, vv * f.k.z)); y2 = Sa2 * f.r.z;
            Sa3 = fmaf(Sa3, f.w.w, fmaf(tmp, f.b.w, vv * f.k.w)); y3 = Sa3 * f.r.w;
            float ypart = (y0 + y1) + (y2 + y3);
            float yo = ypart + __shfl_xor(ypart, 32, 64);   // pair jg and jg^8

            u_cur = (((upart + x01) + (x02 + x03)) + ((x04 + x05) + (x06 + x07)))
                  + (((x08 + x09) + (x10 + x11)) + ((x12 + x13) + (x14 + x15)));
            tmp_prev = tmp; v_prev = vv;

            if (jg < 8) yp8[ybase + t * CC] = f2bf(yo);
        };

        loadfrag(f0, 0);
        loadfrag(f1, 1);
        loadfrag(f2, 2);
        loadfrag(f3, 3);

        for (int t = 0; t < TT; t += 4) {
            stepf(f0, f1, t);
            if (t + 4 < TT) loadfrag(f0, t + 4);
            stepf(f1, f2, t + 1);
            if (t + 5 < TT) loadfrag(f1, t + 5);
            stepf(f2, f3, t + 2);
            if (t + 6 < TT) loadfrag(f2, t + 6);
            stepf(f3, f0, t + 3);      // fn=f0 reloaded 3 steps ago with t+4
            if (t + 7 < TT) loadfrag(f3, t + 7);
        }
        // final iteration: stale fn at t=2047 computes u for t=2048, never used
        return;
    }

    // ---------------- gate lora-out GEMM path ----------------
    // gbuf_b(t,c) = sum_k gw2[c][k] * ghh_b[k][t]   (K=192, TOUT epilogue)
    {
        const int gb = blockIdx.x - 384;       // 0..767
        const int n0t = (gb & 31) * 64;        // T tile
        const int rest = gb >> 5;              // 0..23
        const int m0t = (rest % 12) * 64;      // C tile (768/64)
        const int bz  = rest / 12;             // batch
        const float* A  = gw2;                           // (768 x 192)
        const float* Bm = ghh + (size_t)bz * (192L * TT);
        float* Cm = gbuf + (size_t)bz * ((long)TT * CC);
        const int tid = threadIdx.x;

        __shared__ float As[16][64];
        __shared__ float Bs[16][64];

        const int mi = (tid & 15) * 4, ni = (tid >> 4) * 4;  // TOUT layout
        float acc[4][4];
#pragma unroll
        for (int i = 0; i < 4; ++i)
#pragma unroll
            for (int j = 0; j < 4; ++j) acc[i][j] = 0.f;

        for (int k0 = 0; k0 < 192; k0 += 16) {
            {
                const int row = tid >> 2, kc = (tid & 3) * 4;
                float4 av = *(const float4*)&A[(size_t)(m0t + row) * 192 + k0 + kc];
                As[kc + 0][row] = av.x; As[kc + 1][row] = av.y;
                As[kc + 2][row] = av.z; As[kc + 3][row] = av.w;
            }
            {
                const int krow = tid >> 4, tc = (tid & 15) * 4;
                *(float4*)&Bs[krow][tc] = *(const float4*)&Bm[(size_t)(k0 + krow) * TT + n0t + tc];
            }
            __syncthreads();
#pragma unroll
            for (int kk = 0; kk < 16; ++kk) {
                float4 a4 = *(const float4*)&As[kk][mi];
                float4 b4 = *(const float4*)&Bs[kk][ni];
                float am[4] = {a4.x, a4.y, a4.z, a4.w};
                float bn[4] = {b4.x, b4.y, b4.z, b4.w};
#pragma unroll
                for (int i = 0; i < 4; ++i)
#pragma unroll
                    for (int j = 0; j < 4; ++j) acc[i][j] = fmaf(am[i], bn[j], acc[i][j]);
            }
            __syncthreads();
        }
        const int mbase = m0t + mi, nbase = n0t + ni;
#pragma unroll
        for (int j = 0; j < 4; ++j) {
            float4 o = {acc[0][j], acc[1][j], acc[2][j], acc[3][j]};
            *(float4*)&Cm[(size_t)(nbase + j) * CC + mbase] = o;
        }
    }
}

// ---------------------------------------------------------------------------
// E2: sum 8 bf16 y-partials, RMSNorm*lnw + (sum_head r*k*faaaa)*v, *g -> bf16 z
// ---------------------------------------------------------------------------
__global__ __launch_bounds__(256) void e2_kernel(
    const unsigned short* __restrict__ yp8, const float* __restrict__ rA,
    const float* __restrict__ kA, const float* __restrict__ vA,
    const float* __restrict__ gA, const float* __restrict__ faaaa,
    const float* __restrict__ lnw, unsigned short* __restrict__ zB)
{
    const int bt = blockIdx.x;
    const int b = bt / TT, t = bt - b * TT;
    const size_t base = (size_t)bt * CC;
    const int tid = threadIdx.x;
    const int wave = tid >> 6;
    __shared__ float red[4];
    __shared__ float rk[12];

    float yv[3];
    float ss = 0.f;
#pragma unroll
    for (int ch = 0; ch < 3; ++ch) {
        int c = ch * 256 + tid;
        float y = 0.f;
#pragma unroll
        for (int jg = 0; jg < 8; ++jg)
            y += bf2f(yp8[((size_t)(jg * BB + b) * TT + t) * CC + c]);
        yv[ch] = y;
        ss = fmaf(y, y, ss);
        float p = rA[base + c] * kA[base + c] * faaaa[c];
#pragma unroll
        for (int off = 32; off; off >>= 1) p += __shfl_xor(p, off, 64);
        if ((tid & 63) == 0) rk[ch * 4 + wave] = p;
    }
#pragma unroll
    for (int off = 32; off; off >>= 1) ss += __shfl_xor(ss, off, 64);
    if ((tid & 63) == 0) red[wave] = ss;
    __syncthreads();
    const float total = red[0] + red[1] + red[2] + red[3];
    const float scale = rsqrtf(total / (float)CC + 1e-5f);
#pragma unroll
    for (int ch = 0; ch < 3; ++ch) {
        int c = ch * 256 + tid;
        float out = yv[ch] * scale * lnw[c] + rk[c >> 6] * vA[base + c];
        zB[base + c] = f2bf(out * gA[base + c]);
    }
}

// ---------------------------------------------------------------------------
extern "C" void kernel_launch(void* const* d_in, const int* in_sizes, int n_in,
                              void* d_out, int out_size, void* d_ws, size_t ws_size,
                              hipStream_t stream)
{
    (void)in_sizes; (void)n_in; (void)out_size; (void)ws_size;
    const float* x        = (const float*)d_in[0];
    const float* tmaa_r   = (const float*)d_in[2];
    const float* tmaa_w   = (const float*)d_in[3];
    const float* tmaa_k   = (const float*)d_in[4];
    const float* tmaa_v   = (const float*)d_in[5];
    const float* tmaa_a   = (const float*)d_in[6];
    const float* tmaa_g   = (const float*)d_in[7];
    const float* tdecay   = (const float*)d_in[8];
    const float* tfaaaa   = (const float*)d_in[9];
    const float* taaaaa   = (const float*)d_in[10];
    const float* maa_w1   = (const float*)d_in[11];
    const float* maa_w2   = (const float*)d_in[12];
    const float* decay_w1 = (const float*)d_in[13];
    const float* decay_w2 = (const float*)d_in[14];
    const float* aaa_w1   = (const float*)d_in[15];
    const float* aaa_w2   = (const float*)d_in[16];
    const float* kkk_w1   = (const float*)d_in[17];
    const float* kkk_w2   = (const float*)d_in[18];
    const float* gate_w1  = (const float*)d_in[19];
    const float* gate_w2  = (const float*)d_in[20];
    const float* w_key    = (const float*)d_in[21];
    const float* w_value  = (const float*)d_in[22];
    const float* w_recept = (const float*)d_in[23];
    const float* w_output = (const float*)d_in[24];
    const float* lnw      = (const float*)d_in[25];
    float* out = (float*)d_out;

    float* ws   = (float*)d_ws;
    float* paux = ws;                 // 6*768
    float* tm   = ws + 8192;          // S1 (dead after mix GEMM; bg reuses it)
    float* X6   = tm + S1;            // 6*FF
    float* dh   = X6 + 6 * FF;        // B*64*T = 262144
    float* ah   = dh + 262144;
    float* kh   = ah + 262144;
    float* gh   = kh + 262144;        // B*192*T = 786432
    float* gbuf = gh + 786432;        // FF
    // bf16 region
    unsigned short* yp8 = (unsigned short*)(gbuf + FF);  // 8*FF  (y partials)
    unsigned short* X6b = yp8 + 8 * FF;                  // 3*FF  (xr,xk,xv bf16 (C,T))
    unsigned short* zb  = X6b + 3 * FF;                  // FF
    unsigned short* wb  = zb + FF;                       // 5*294912
    unsigned short* xtb = wb + 5L * 294912;              // FF    (x bf16 (T,C))
    unsigned short* X6t = xtb + FF;                      // 3*FF  (xr,xk,xv bf16 (T,C))

    float* xw = X6 + 1 * FF; float* xk = X6 + 2 * FF;
    float* xa = X6 + 4 * FF; float* xg = X6 + 5 * FF;
    float* wwB = X6 + 0 * FF; float* rB  = X6 + 1 * FF; float* aaB = X6 + 2 * FF;
    float* b2B = X6 + 3 * FF; float* kB  = X6 + 4 * FF; float* vB  = X6 + 5 * FF;

    // beta/gamma buffer reuses the (dead by then) tm region: 24*2048 float2
    float2* bgbuf = (float2*)tm;

    const long CT = (long)CC * TT;        // 1572864
    const long TC = (long)TT * CC;        // 1572864

    // wcvt + pack_aux merged
    wcvt_kernel<<<dim3(5761), 256, 0, stream>>>(
        w_recept, w_key, w_value, w_output, maa_w1, wb,
        tmaa_r, tmaa_w, tmaa_k, tmaa_v, tmaa_a, tmaa_g, paux);
    xtr_kernel<<<dim3(32, 12, 2), 256, 0, stream>>>(x, xtb);

    // tm = tanh(maa_w1 @ x)  via bf16 MFMA
    maaw1_mfma_kernel<<<dim3(16, 3, 2), 256, 0, stream>>>(wb + 4L * 294912, xtb, tm);

    // X6[n] = x * (paux[n] + maa_w2[n]^T @ tm_n); bf16 side-write r/k/v;
    // fp32 store skipped for slots 0,3 (never read as fp32)
    gemm_kernel<1,0,0,2><<<dim3(32, 12, 12), 256, 0, stream>>>(
        maa_w2, tm, X6, paux, x,
        64, 768, TT, TT, 6,
        0, 64L * 768, 384L * TT, 64L * TT, CT, FF, 768, CT, X6b);

    // transpose bf16 conv inputs (C,T) -> (T,C)
    btr_kernel<<<dim3(32, 12, 6), 256, 0, stream>>>(X6b, X6t);

    // merged lora hiddens (decay/aaa/kkk/gate _w1, tanh)
    lorah_kernel<<<dim3(32, 3, 8), 256, 0, stream>>>(
        decay_w1, aaa_w1, kkk_w1, gate_w1, xw, xa, xk, xg, dh, ah, kh, gh);

    // merged 3 input convs via bf16 MFMA -> rB/kB/vB (fp32 (B,T,C))
    convs3_mfma_kernel<<<dim3(16, 3, 12), 256, 0, stream>>>(wb, X6t, X6);

    // merged lora-outs (decay/aaa/kkk) -> (B,T,C); gate GEMM lives in wkv launch
    loraout_kernel<<<dim3(32, 12, 6), 256, 0, stream>>>(
        decay_w2, aaa_w2, kkk_w2, dh, ah, kh, tdecay, taaaaa, wwB, b2B, aaB);

    // E1: build aa (over kvec slot) and b2 (over a slot)
    e1_kernel<<<dim3(BB * TT), 256, 0, stream>>>(kB, aaB, b2B);

    // BG: input-only dots beta/gamma for the pipelined tmp recurrence
    bg_kernel<<<dim3(BB * TT), 256, 0, stream>>>(b2B, aaB, kB, bgbuf);

    // WKV v16: R=4 beta/gamma-pipelined recurrence + fused gate GEMM
    wkv_gate_kernel<<<dim3(1152), 256, 0, stream>>>(
        rB, wwB, kB, vB, aaB, b2B, bgbuf, yp8, gate_w2, gh, gbuf);

    // E2: sum partials + rmsnorm + faaaa bonus + gate -> bf16 z
    e2_kernel<<<dim3(BB * TT), 256, 0, stream>>>(yp8, rB, kB, vB, gbuf, tfaaaa, lnw, zb);

    // final grouped conv via bf16 MFMA: z (B,T,C) -> out (B,C,T)
    convout_mfma_kernel<<<dim3(16, 3, 4), 256, 0, stream>>>(wb + 3L * 294912, zb, out);
}

// Round 6
// 768.027 us; speedup vs baseline: 1.3976x; 1.3976x over previous
//
#include <hip/hip_runtime.h>
#include <math.h>

// Problem constants
#define BB 2
#define TT 2048
#define CC 768
#define HH 12
#define NN 64
#define GG 2
#define CG 384   // C/G
#define FF 3145728L   // B*C*T
#define S1 1572864L   // B*384*T

typedef __attribute__((ext_vector_type(8))) short bf8frag;   // 8 bf16 (4 VGPRs)
typedef __attribute__((ext_vector_type(4))) float f4acc;     // 4 fp32 acc

__device__ inline unsigned short f2bf(float x) {
    union { float f; unsigned u; } v; v.f = x;
    unsigned r = v.u + 0x7FFFu + ((v.u >> 16) & 1u);   // RNE
    return (unsigned short)(r >> 16);
}
__device__ inline float bf2f(unsigned short u) {
    union { unsigned u; float f; } v; v.u = ((unsigned)u) << 16;
    return v.f;
}

// ---------------------------------------------------------------------------
// Generic fp32 tiled GEMM v1: 64x64 tile, 256 threads, 4x4 micro-tile.
// bfout: optional bf16 side-write (mix GEMM emits bf16 xr/xk/xv copies).
// MODE==2: fp32 store skipped for zi in {0,3} (xr/xv fp32 never read).
// ---------------------------------------------------------------------------
template<int ATRANS, int BTRANS, int TOUT, int MODE>
__global__ __launch_bounds__(256) void gemm_kernel(
    const float* __restrict__ A, const float* __restrict__ Bm, float* __restrict__ Cm,
    const float* __restrict__ aux, const float* __restrict__ aux2,
    int K, int ldA, int ldB, int ldC, int zInner,
    long sA_o, long sA_i, long sB_o, long sB_i, long sC_o, long sC_i,
    long sAux_i, long sAux2_o, unsigned short* bfout)
{
    const int zo = blockIdx.z / zInner;
    const int zi = blockIdx.z % zInner;
    A  += (size_t)zo * sA_o + (size_t)zi * sA_i;
    Bm += (size_t)zo * sB_o + (size_t)zi * sB_i;
    Cm += (size_t)zo * sC_o + (size_t)zi * sC_i;
    if (MODE == 2) { aux += (size_t)zi * sAux_i; aux2 += (size_t)zo * sAux2_o; }

    const int m0t = blockIdx.y * 64;
    const int n0t = blockIdx.x * 64;
    const int tid = threadIdx.x;

    __shared__ float As[16][64];
    __shared__ float Bs[16][64];

    int mi, ni;
    if (TOUT) { mi = (tid & 15) * 4; ni = (tid >> 4) * 4; }
    else      { ni = (tid & 15) * 4; mi = (tid >> 4) * 4; }

    float acc[4][4];
#pragma unroll
    for (int i = 0; i < 4; ++i)
#pragma unroll
        for (int j = 0; j < 4; ++j) acc[i][j] = 0.f;

    for (int k0 = 0; k0 < K; k0 += 16) {
        if (!ATRANS) {
            const int row = tid >> 2;
            const int kc  = (tid & 3) * 4;
            float4 av = *(const float4*)&A[(size_t)(m0t + row) * ldA + k0 + kc];
            As[kc + 0][row] = av.x; As[kc + 1][row] = av.y;
            As[kc + 2][row] = av.z; As[kc + 3][row] = av.w;
        } else {
            const int krow = tid >> 4;
            const int mc   = (tid & 15) * 4;
            *(float4*)&As[krow][mc] = *(const float4*)&A[(size_t)(k0 + krow) * ldA + m0t + mc];
        }
        if (!BTRANS) {
            const int krow = tid >> 4;
            const int tc   = (tid & 15) * 4;
            *(float4*)&Bs[krow][tc] = *(const float4*)&Bm[(size_t)(k0 + krow) * ldB + n0t + tc];
        } else {
            const int trow = tid >> 2;
            const int kc   = (tid & 3) * 4;
            float4 bv = *(const float4*)&Bm[(size_t)(n0t + trow) * ldB + k0 + kc];
            Bs[kc + 0][trow] = bv.x; Bs[kc + 1][trow] = bv.y;
            Bs[kc + 2][trow] = bv.z; Bs[kc + 3][trow] = bv.w;
        }
        __syncthreads();
#pragma unroll
        for (int kk = 0; kk < 16; ++kk) {
            float4 a4 = *(const float4*)&As[kk][mi];
            float4 b4 = *(const float4*)&Bs[kk][ni];
            float am[4] = {a4.x, a4.y, a4.z, a4.w};
            float bn[4] = {b4.x, b4.y, b4.z, b4.w};
#pragma unroll
            for (int i = 0; i < 4; ++i)
#pragma unroll
                for (int j = 0; j < 4; ++j) acc[i][j] = fmaf(am[i], bn[j], acc[i][j]);
        }
        __syncthreads();
    }

    const int mbase = m0t + mi, nbase = n0t + ni;
#pragma unroll
    for (int i = 0; i < 4; ++i) {
        float4 xv;
        if (MODE == 2) xv = *(const float4*)&aux2[(size_t)(mbase + i) * ldC + nbase];
        float xa[4] = {0.f, 0.f, 0.f, 0.f};
        if (MODE == 2) { xa[0] = xv.x; xa[1] = xv.y; xa[2] = xv.z; xa[3] = xv.w; }
#pragma unroll
        for (int j = 0; j < 4; ++j) {
            float v = acc[i][j];
            if (MODE == 1) v = tanhf(v);
            else if (MODE == 2) v = xa[j] * (aux[mbase + i] + v);
            else if (MODE == 3) {
                float u  = aux[mbase + i] + v;
                float sp = fmaxf(-u, 0.f) + log1pf(expf(-fabsf(u)));  // softplus(-u)
                float wl = -sp - 0.5f;
                v = expf(-expf(wl));
            } else if (MODE == 4) {
                float u = aux[mbase + i] + v;
                v = 1.f / (1.f + expf(-u));
            }
            acc[i][j] = v;
        }
    }
    if (!TOUT) {
        const bool skipf = (MODE == 2) && (bfout != nullptr) && (zi == 0 || zi == 3);
        if (!skipf) {
#pragma unroll
            for (int i = 0; i < 4; ++i) {
                float4 o = {acc[i][0], acc[i][1], acc[i][2], acc[i][3]};
                *(float4*)&Cm[(size_t)(mbase + i) * ldC + nbase] = o;
            }
        }
        // bf16 side-write for MFMA conv inputs: slots n in {0:xr, 2:xk, 3:xv}
        if (MODE == 2 && bfout != nullptr) {
            int sidx = (zi == 0) ? 0 : (zi == 2) ? 1 : (zi == 3) ? 2 : -1;
            if (sidx >= 0) {
                unsigned short* bp = bfout + (size_t)sidx * FF + (size_t)zo * ((long)CC * TT);
#pragma unroll
                for (int i = 0; i < 4; ++i) {
                    ushort4 o = {f2bf(acc[i][0]), f2bf(acc[i][1]), f2bf(acc[i][2]), f2bf(acc[i][3])};
                    *(ushort4*)&bp[(size_t)(mbase + i) * ldC + nbase] = o;
                }
            }
        }
    } else {
#pragma unroll
        for (int j = 0; j < 4; ++j) {
            float4 o = {acc[0][j], acc[1][j], acc[2][j], acc[3][j]};
            *(float4*)&Cm[(size_t)(nbase + j) * ldC + mbase] = o;
        }
    }
}

// ---------------------------------------------------------------------------
// Merged lora-hidden GEMMs (decay/aaa/kkk/gate _w1): tanh(W @ x_slot).
// grid (32,3,8): z = which*2 + b; which<3 uses only blockIdx.y==0 (M=64).
// ---------------------------------------------------------------------------
__global__ __launch_bounds__(256) void lorah_kernel(
    const float* __restrict__ w0, const float* __restrict__ w1,
    const float* __restrict__ w2, const float* __restrict__ w3,
    const float* __restrict__ x0, const float* __restrict__ x1,
    const float* __restrict__ x2, const float* __restrict__ x3,
    float* __restrict__ o0, float* __restrict__ o1,
    float* __restrict__ o2, float* __restrict__ o3)
{
    const int z = blockIdx.z;
    const int which = z >> 1, bz = z & 1;
    if (which < 3 && blockIdx.y > 0) return;
    const float* A; const float* Bm; float* Cm; int M;
    if (which == 0)      { A = w0; Bm = x0; Cm = o0; M = 64; }
    else if (which == 1) { A = w1; Bm = x1; Cm = o1; M = 64; }
    else if (which == 2) { A = w2; Bm = x2; Cm = o2; M = 64; }
    else                 { A = w3; Bm = x3; Cm = o3; M = 192; }
    Bm += (size_t)bz * ((long)CC * TT);
    Cm += (size_t)bz * ((long)M * TT);

    const int m0t = blockIdx.y * 64;
    const int n0t = blockIdx.x * 64;
    const int tid = threadIdx.x;

    __shared__ float As[16][64];
    __shared__ float Bs[16][64];

    const int ni = (tid & 15) * 4, mi = (tid >> 4) * 4;
    float acc[4][4];
#pragma unroll
    for (int i = 0; i < 4; ++i)
#pragma unroll
        for (int j = 0; j < 4; ++j) acc[i][j] = 0.f;

    for (int k0 = 0; k0 < CC; k0 += 16) {
        {
            const int row = tid >> 2, kc = (tid & 3) * 4;
            float4 av = *(const float4*)&A[(size_t)(m0t + row) * CC + k0 + kc];
            As[kc + 0][row] = av.x; As[kc + 1][row] = av.y;
            As[kc + 2][row] = av.z; As[kc + 3][row] = av.w;
        }
        {
            const int krow = tid >> 4, tc = (tid & 15) * 4;
            *(float4*)&Bs[krow][tc] = *(const float4*)&Bm[(size_t)(k0 + krow) * TT + n0t + tc];
        }
        __syncthreads();
#pragma unroll
        for (int kk = 0; kk < 16; ++kk) {
            float4 a4 = *(const float4*)&As[kk][mi];
            float4 b4 = *(const float4*)&Bs[kk][ni];
            float am[4] = {a4.x, a4.y, a4.z, a4.w};
            float bn[4] = {b4.x, b4.y, b4.z, b4.w};
#pragma unroll
            for (int i = 0; i < 4; ++i)
#pragma unroll
                for (int j = 0; j < 4; ++j) acc[i][j] = fmaf(am[i], bn[j], acc[i][j]);
        }
        __syncthreads();
    }
    const int mbase = m0t + mi, nbase = n0t + ni;
#pragma unroll
    for (int i = 0; i < 4; ++i) {
        float4 o = {tanhf(acc[i][0]), tanhf(acc[i][1]), tanhf(acc[i][2]), tanhf(acc[i][3])};
        *(float4*)&Cm[(size_t)(mbase + i) * TT + nbase] = o;
    }
}

// ---------------------------------------------------------------------------
// Merged lora-out GEMMs (decay/aaa/kkk _w2): one launch, runtime epilogue.
// grid (32,12,6): z = which*2 + b. K=64 for all three; TOUT layout.
//   which 0: ww = exp(-exp(-softplus(-(tdecay + v)) - 0.5))
//   which 1: b2-slot = sigmoid(taaaaa + v)
//   which 2: kvec (raw)
// ---------------------------------------------------------------------------
__global__ __launch_bounds__(256) void loraout_kernel(
    const float* __restrict__ dw2, const float* __restrict__ aw2,
    const float* __restrict__ kw2,
    const float* __restrict__ dhh, const float* __restrict__ ahh,
    const float* __restrict__ khh,
    const float* __restrict__ tdecay, const float* __restrict__ taaaaa,
    float* __restrict__ wwB, float* __restrict__ b2B, float* __restrict__ aaB)
{
    const int z = blockIdx.z;
    const int which = z >> 1, bz = z & 1;
    const float* A; const float* Bm; float* Cm; const float* aux;
    if (which == 0)      { A = dw2; Bm = dhh; Cm = wwB; aux = tdecay; }
    else if (which == 1) { A = aw2; Bm = ahh; Cm = b2B; aux = taaaaa; }
    else                 { A = kw2; Bm = khh; Cm = aaB; aux = nullptr; }
    Bm += (size_t)bz * (64L * TT);
    Cm += (size_t)bz * ((long)TT * CC);

    const int m0t = blockIdx.y * 64;
    const int n0t = blockIdx.x * 64;
    const int tid = threadIdx.x;

    __shared__ float As[16][64];
    __shared__ float Bs[16][64];

    const int mi = (tid & 15) * 4, ni = (tid >> 4) * 4;   // TOUT layout
    float acc[4][4];
#pragma unroll
    for (int i = 0; i < 4; ++i)
#pragma unroll
        for (int j = 0; j < 4; ++j) acc[i][j] = 0.f;

    for (int k0 = 0; k0 < 64; k0 += 16) {
        {
            const int row = tid >> 2, kc = (tid & 3) * 4;
            float4 av = *(const float4*)&A[(size_t)(m0t + row) * 64 + k0 + kc];
            As[kc + 0][row] = av.x; As[kc + 1][row] = av.y;
            As[kc + 2][row] = av.z; As[kc + 3][row] = av.w;
        }
        {
            const int krow = tid >> 4, tc = (tid & 15) * 4;
            *(float4*)&Bs[krow][tc] = *(const float4*)&Bm[(size_t)(k0 + krow) * TT + n0t + tc];
        }
        __syncthreads();
#pragma unroll
        for (int kk = 0; kk < 16; ++kk) {
            float4 a4 = *(const float4*)&As[kk][mi];
            float4 b4 = *(const float4*)&Bs[kk][ni];
            float am[4] = {a4.x, a4.y, a4.z, a4.w};
            float bn[4] = {b4.x, b4.y, b4.z, b4.w};
#pragma unroll
            for (int i = 0; i < 4; ++i)
#pragma unroll
                for (int j = 0; j < 4; ++j) acc[i][j] = fmaf(am[i], bn[j], acc[i][j]);
        }
        __syncthreads();
    }
    const int mbase = m0t + mi, nbase = n0t + ni;
#pragma unroll
    for (int i = 0; i < 4; ++i) {
#pragma unroll
        for (int j = 0; j < 4; ++j) {
            float v = acc[i][j];
            if (which == 0) {
                float u  = aux[mbase + i] + v;
                float sp = fmaxf(-u, 0.f) + log1pf(expf(-fabsf(u)));  // softplus(-u)
                v = expf(-expf(-sp - 0.5f));
            } else if (which == 1) {
                float u = aux[mbase + i] + v;
                v = 1.f / (1.f + expf(-u));
            }
            acc[i][j] = v;
        }
    }
#pragma unroll
    for (int j = 0; j < 4; ++j) {
        float4 o = {acc[0][j], acc[1][j], acc[2][j], acc[3][j]};
        *(float4*)&Cm[(size_t)(nbase + j) * CC + mbase] = o;
    }
}

// ---------------------------------------------------------------------------
// Merged 3 input convs via bf16 MFMA: grid (16,3,12), z = conv*4 + b*2 + g.
// ---------------------------------------------------------------------------
__global__ __launch_bounds__(256) void convs3_mfma_kernel(
    const unsigned short* __restrict__ wball, const unsigned short* __restrict__ X6t,
    float* __restrict__ X6)
{
    const int z = blockIdx.z;
    const int conv = z >> 2, bg = z & 3, b = bg >> 1, g = bg & 1;
    const unsigned short* Wb = wball + (size_t)conv * 294912;
    const unsigned short* Xb = X6t + (size_t)conv * FF;
    const int oslot = (conv == 0) ? 1 : (conv == 1) ? 4 : 5;
    float* Cout = X6 + (size_t)oslot * FF;

    const int t0 = blockIdx.x * 128;
    const int m0 = blockIdx.y * 128;
    const int tid = threadIdx.x;
    const int wave = tid >> 6, lane = tid & 63;
    const int lq = lane >> 4, lr = lane & 15;

    __shared__ unsigned short Ws[128 * 40];
    __shared__ unsigned short Xs[128 * 40];

    const unsigned short* Wg = Wb + (size_t)g * (CG * CG);
    const long xbase = (long)b * (long)TT * CC;

    f4acc acc0[8], acc1[8];
#pragma unroll
    for (int j = 0; j < 8; ++j) { acc0[j] = (f4acc)0.f; acc1[j] = (f4acc)0.f; }

    for (int k0 = 0; k0 < CG; k0 += 32) {
        {
            const int m = tid >> 1, kc = (tid & 1) * 16;
            const unsigned short* src = Wg + (size_t)(m0 + m) * CG + k0 + kc;
            *(bf8frag*)&Ws[m * 40 + kc]     = *(const bf8frag*)src;
            *(bf8frag*)&Ws[m * 40 + kc + 8] = *(const bf8frag*)(src + 8);
        }
        {
            const int t = tid >> 1, kc = (tid & 1) * 16;
            const unsigned short* src = Xb + xbase + (long)(t0 + t) * CC + g * CG + k0 + kc;
            *(bf8frag*)&Xs[t * 40 + kc]     = *(const bf8frag*)src;
            *(bf8frag*)&Xs[t * 40 + kc + 8] = *(const bf8frag*)(src + 8);
        }
        __syncthreads();

        bf8frag a0 = *(const bf8frag*)&Ws[(32 * wave + lr) * 40 + lq * 8];
        bf8frag a1 = *(const bf8frag*)&Ws[(32 * wave + 16 + lr) * 40 + lq * 8];
#pragma unroll
        for (int nj = 0; nj < 8; ++nj) {
            bf8frag bb = *(const bf8frag*)&Xs[(16 * nj + lr) * 40 + lq * 8];
            acc0[nj] = __builtin_amdgcn_mfma_f32_16x16x32_bf16(a0, bb, acc0[nj], 0, 0, 0);
            acc1[nj] = __builtin_amdgcn_mfma_f32_16x16x32_bf16(a1, bb, acc1[nj], 0, 0, 0);
        }
        __syncthreads();
    }

#pragma unroll
    for (int fi = 0; fi < 2; ++fi) {
        const int cbase = m0 + 32 * wave + 16 * fi + lq * 4;
#pragma unroll
        for (int nj = 0; nj < 8; ++nj) {
            const f4acc av = fi ? acc1[nj] : acc0[nj];
            const int t = t0 + 16 * nj + lr;
            float4 o = {av[0], av[1], av[2], av[3]};
            *(float4*)&Cout[(long)b * (long)TT * CC + (long)t * CC + g * CG + cbase] = o;
        }
    }
}

// ---------------------------------------------------------------------------
// Output conv via bf16 MFMA: z (B,T,C) bf16 -> out (B,C,T) fp32.
// ---------------------------------------------------------------------------
__global__ __launch_bounds__(256) void convout_mfma_kernel(
    const unsigned short* __restrict__ Wb, const unsigned short* __restrict__ Xb,
    float* __restrict__ Cout)
{
    const int bz = blockIdx.z; const int b = bz >> 1, g = bz & 1;
    const int t0 = blockIdx.x * 128;
    const int m0 = blockIdx.y * 128;
    const int tid = threadIdx.x;
    const int wave = tid >> 6, lane = tid & 63;
    const int lq = lane >> 4, lr = lane & 15;

    __shared__ unsigned short Ws[128 * 40];
    __shared__ unsigned short Xs[128 * 40];

    const unsigned short* Wg = Wb + (size_t)g * (CG * CG);
    const long xbase = (long)b * (long)TT * CC;

    f4acc acc0[8], acc1[8];
#pragma unroll
    for (int j = 0; j < 8; ++j) { acc0[j] = (f4acc)0.f; acc1[j] = (f4acc)0.f; }

    for (int k0 = 0; k0 < CG; k0 += 32) {
        {
            const int m = tid >> 1, kc = (tid & 1) * 16;
            const unsigned short* src = Wg + (size_t)(m0 + m) * CG + k0 + kc;
            *(bf8frag*)&Ws[m * 40 + kc]     = *(const bf8frag*)src;
            *(bf8frag*)&Ws[m * 40 + kc + 8] = *(const bf8frag*)(src + 8);
        }
        {
            const int t = tid >> 1, kc = (tid & 1) * 16;
            const unsigned short* src = Xb + xbase + (long)(t0 + t) * CC + g * CG + k0 + kc;
            *(bf8frag*)&Xs[t * 40 + kc]     = *(const bf8frag*)src;
            *(bf8frag*)&Xs[t * 40 + kc + 8] = *(const bf8frag*)(src + 8);
        }
        __syncthreads();

        bf8frag a0 = *(const bf8frag*)&Ws[(32 * wave + lr) * 40 + lq * 8];
        bf8frag a1 = *(const bf8frag*)&Ws[(32 * wave + 16 + lr) * 40 + lq * 8];
#pragma unroll
        for (int nj = 0; nj < 8; ++nj) {
            bf8frag bb = *(const bf8frag*)&Xs[(16 * nj + lr) * 40 + lq * 8];
            acc0[nj] = __builtin_amdgcn_mfma_f32_16x16x32_bf16(a0, bb, acc0[nj], 0, 0, 0);
            acc1[nj] = __builtin_amdgcn_mfma_f32_16x16x32_bf16(a1, bb, acc1[nj], 0, 0, 0);
        }
        __syncthreads();
    }

#pragma unroll
    for (int fi = 0; fi < 2; ++fi) {
        const int cbase = m0 + 32 * wave + 16 * fi + lq * 4;
#pragma unroll
        for (int nj = 0; nj < 8; ++nj) {
            const f4acc av = fi ? acc1[nj] : acc0[nj];
            const int t = t0 + 16 * nj + lr;
#pragma unroll
            for (int i = 0; i < 4; ++i)
                Cout[(long)b * (long)CC * TT + (long)(g * CG + cbase + i) * TT + t] = av[i];
        }
    }
}

// ---------------------------------------------------------------------------
// maa_w1 bf16 MFMA GEMM: tm(b,384,T) = tanh( W(384x768) @ x(b,768,T) ).
// ---------------------------------------------------------------------------
__global__ __launch_bounds__(256) void maaw1_mfma_kernel(
    const unsigned short* __restrict__ Wb, const unsigned short* __restrict__ Xb,
    float* __restrict__ Cout)
{
    const int b = blockIdx.z;
    const int t0 = blockIdx.x * 128;
    const int m0 = blockIdx.y * 128;
    const int tid = threadIdx.x;
    const int wave = tid >> 6, lane = tid & 63;
    const int lq = lane >> 4, lr = lane & 15;

    __shared__ unsigned short Ws[128 * 40];
    __shared__ unsigned short Xs[128 * 40];

    const long xbase = (long)b * (long)TT * CC;

    f4acc acc0[8], acc1[8];
#pragma unroll
    for (int j = 0; j < 8; ++j) { acc0[j] = (f4acc)0.f; acc1[j] = (f4acc)0.f; }

    for (int k0 = 0; k0 < CC; k0 += 32) {
        {
            const int m = tid >> 1, kc = (tid & 1) * 16;
            const unsigned short* src = Wb + (size_t)(m0 + m) * CC + k0 + kc;
            *(bf8frag*)&Ws[m * 40 + kc]     = *(const bf8frag*)src;
            *(bf8frag*)&Ws[m * 40 + kc + 8] = *(const bf8frag*)(src + 8);
        }
        {
            const int t = tid >> 1, kc = (tid & 1) * 16;
            const unsigned short* src = Xb + xbase + (long)(t0 + t) * CC + k0 + kc;
            *(bf8frag*)&Xs[t * 40 + kc]     = *(const bf8frag*)src;
            *(bf8frag*)&Xs[t * 40 + kc + 8] = *(const bf8frag*)(src + 8);
        }
        __syncthreads();

        bf8frag a0 = *(const bf8frag*)&Ws[(32 * wave + lr) * 40 + lq * 8];
        bf8frag a1 = *(const bf8frag*)&Ws[(32 * wave + 16 + lr) * 40 + lq * 8];
#pragma unroll
        for (int nj = 0; nj < 8; ++nj) {
            bf8frag bb = *(const bf8frag*)&Xs[(16 * nj + lr) * 40 + lq * 8];
            acc0[nj] = __builtin_amdgcn_mfma_f32_16x16x32_bf16(a0, bb, acc0[nj], 0, 0, 0);
            acc1[nj] = __builtin_amdgcn_mfma_f32_16x16x32_bf16(a1, bb, acc1[nj], 0, 0, 0);
        }
        __syncthreads();
    }

#pragma unroll
    for (int fi = 0; fi < 2; ++fi) {
        const int m = m0 + 32 * wave + 16 * fi + lq * 4;
#pragma unroll
        for (int nj = 0; nj < 8; ++nj) {
            const f4acc av = fi ? acc1[nj] : acc0[nj];
            const int t = t0 + 16 * nj + lr;
#pragma unroll
            for (int i = 0; i < 4; ++i)
                Cout[(long)b * 384 * TT + (long)(m + i) * TT + t] = tanhf(av[i]);
        }
    }
}

// ---------------------------------------------------------------------------
// btr: bf16 (C,T) -> (T,C) transpose (LDS 64x64 tiles)
// ---------------------------------------------------------------------------
__global__ __launch_bounds__(256) void btr_kernel(const unsigned short* __restrict__ xin,
                                                  unsigned short* __restrict__ xout)
{
    __shared__ unsigned short L[64][68];
    const int t0 = blockIdx.x * 64, c0 = blockIdx.y * 64;
    const int s = blockIdx.z >> 1, b = blockIdx.z & 1;
    const int tid = threadIdx.x;
    const int lr = tid >> 4, lc = (tid & 15) * 4;
    const size_t ibase = (size_t)s * FF + (size_t)b * CC * TT;
    const size_t obase = (size_t)s * FF + (size_t)b * TT * CC;
#pragma unroll
    for (int i = 0; i < 4; ++i) {
        int c = lr + i * 16;
        ushort4 v = *(const ushort4*)&xin[ibase + (size_t)(c0 + c) * TT + t0 + lc];
        L[c][lc + 0] = v.x; L[c][lc + 1] = v.y; L[c][lc + 2] = v.z; L[c][lc + 3] = v.w;
    }
    __syncthreads();
#pragma unroll
    for (int i = 0; i < 4; ++i) {
        int t = lr + i * 16;
        ushort4 o = {L[lc + 0][t], L[lc + 1][t], L[lc + 2][t], L[lc + 3][t]};
        *(ushort4*)&xout[obase + (size_t)(t0 + t) * CC + c0 + lc] = o;
    }
}

// ---------------------------------------------------------------------------
// wcvt + pack_aux + xtr merged into one launch:
//   blocks 0..5759    : weight fp32->bf16 convert (5 matrices)
//   blocks 5760..6527 : xtr  x fp32 (B,C,T) -> bf16 (B,T,C)  (was xtr_kernel)
//   block  6528       : pack_aux
// ---------------------------------------------------------------------------
__global__ __launch_bounds__(256) void wcvt_kernel(
    const float* __restrict__ w0, const float* __restrict__ w1,
    const float* __restrict__ w2, const float* __restrict__ w3,
    const float* __restrict__ w4, unsigned short* __restrict__ wb,
    const float* __restrict__ pr, const float* __restrict__ pw,
    const float* __restrict__ pk, const float* __restrict__ pv,
    const float* __restrict__ pa, const float* __restrict__ pg,
    float* __restrict__ paux,
    const float* __restrict__ xin, unsigned short* __restrict__ xout)
{
    __shared__ unsigned short L[64][68];
    const int bid = blockIdx.x;
    if (bid < 5760) {
        const int i = bid * 256 + threadIdx.x;   // total 5*294912
        const int which = i / 294912, r = i - which * 294912;
        const float* s = (which == 0) ? w0 : (which == 1) ? w1 : (which == 2) ? w2
                       : (which == 3) ? w3 : w4;
        wb[i] = f2bf(s[r]);
        return;
    }
    if (bid < 6528) {
        // xtr path: gb in [0,768): x=(gb&31), y=(gb>>5)%12, z=(gb>>5)/12
        const int gb = bid - 5760;
        const int t0 = (gb & 31) * 64;
        const int rest = gb >> 5;
        const int c0 = (rest % 12) * 64;
        const int b  = rest / 12;
        const int tid = threadIdx.x;
        const int lr = tid >> 4, lc = (tid & 15) * 4;
#pragma unroll
        for (int i = 0; i < 4; ++i) {
            int c = lr + i * 16;
            float4 v = *(const float4*)&xin[(size_t)b * CC * TT + (size_t)(c0 + c) * TT + t0 + lc];
            L[c][lc + 0] = f2bf(v.x); L[c][lc + 1] = f2bf(v.y);
            L[c][lc + 2] = f2bf(v.z); L[c][lc + 3] = f2bf(v.w);
        }
        __syncthreads();
#pragma unroll
        for (int i = 0; i < 4; ++i) {
            int t = lr + i * 16;
            ushort4 o = {L[lc + 0][t], L[lc + 1][t], L[lc + 2][t], L[lc + 3][t]};
            *(ushort4*)&xout[(size_t)b * TT * CC + (size_t)(t0 + t) * CC + c0 + lc] = o;
        }
        return;
    }
    // pack_aux path
#pragma unroll
    for (int ch = 0; ch < 3; ++ch) {
        int c = ch * 256 + threadIdx.x;
        paux[0 * CC + c] = 1.f + pr[c];
        paux[1 * CC + c] = 1.f + pw[c];
        paux[2 * CC + c] = 1.f + pk[c];
        paux[3 * CC + c] = 1.f + pv[c];
        paux[4 * CC + c] = 1.f + pa[c];
        paux[5 * CC + c] = 1.f + pg[c];
    }
}

// ---------------------------------------------------------------------------
// E1: per token, kk = k + kvec; per-head L2-normalize; aa=-kkn, b2=kkn*a.
// ---------------------------------------------------------------------------
__global__ __launch_bounds__(256) void e1_kernel(const float* __restrict__ kA,
                                                 float* __restrict__ kvecA,
                                                 float* __restrict__ aA)
{
    const size_t base = (size_t)blockIdx.x * CC;
    const int tid = threadIdx.x;
#pragma unroll
    for (int ch = 0; ch < 3; ++ch) {
        int c = ch * 256 + tid;
        float kk = kA[base + c] + kvecA[base + c];
        float ss = kk * kk;
#pragma unroll
        for (int off = 32; off; off >>= 1) ss += __shfl_xor(ss, off, 64);
        float denom = fmaxf(sqrtf(ss), 1e-12f);
        float kkn = kk / denom;
        float av = aA[base + c];
        kvecA[base + c] = -kkn;       // aa
        aA[base + c]    = kkn * av;   // b2
    }
}

// ---------------------------------------------------------------------------
// WKV-7 v17 = round-3's v14 VERBATIM: exact v11 recurrence (best measured:
// 466 us fused) + gate lora-out GEMM in the latency shadow.
//   blocks 0..191   : v11 wkv, 1 wave (threads 64..255 exit immediately)
//   blocks 192..959 : gate GEMM  gbuf(b,T,C) = (gate_w2 @ gh_b)^T
// Rounds 1/2/5 (beta-gamma pipelined rotations) all regressed: the compiler
// demotes >~130-float live rotations (VGPR 84/108/92 measured) and re-sinks
// loads onto the serial chain. v11 measures ~51% of the single-wave VALU
// issue ceiling -- near the structural floor for this formulation.
// ---------------------------------------------------------------------------
struct WFrag {
    float4 w[2], a[2], b[2], k[2], r[2];
    float vv;
};

__global__ __launch_bounds__(256) void wkv_gate_kernel(
    const float* __restrict__ rA, const float* __restrict__ wA,
    const float* __restrict__ kA, const float* __restrict__ vA,
    const float* __restrict__ aaA, const float* __restrict__ b2A,
    unsigned short* __restrict__ yp8,
    const float* __restrict__ gw2, const float* __restrict__ ghh,
    float* __restrict__ gbuf)
{
    if (blockIdx.x < 192) {
        // ---------------- v11 wkv path (verbatim) ----------------
        if (threadIdx.x >= 64) return;
        const int blk = blockIdx.x;          // rg*24 + bh  (XCD swizzle)
        const int bh = blk % 24, rg = blk / 24;
        const int b = bh / HH, h = bh - b * HH;
        const int lane = threadIdx.x;
        const int jg = lane >> 3, p = lane & 7;
        const int row = rg * 8 + p;
        const int base = b * TT * CC + h * NN;
        const int fo = jg * 8;
        const int ybase = (jg * BB + b) * (TT * CC) + h * NN + row;

        float S[8];
#pragma unroll
        for (int i = 0; i < 8; ++i) S[i] = 0.f;

        WFrag f0, f1, f2;

        auto loadfrag = [&](WFrag& f, int t) {
            const int o = base + t * CC + fo;
#pragma unroll
            for (int q = 0; q < 2; ++q) {
                f.w[q] = *(const float4*)&wA[o + 4 * q];
                f.a[q] = *(const float4*)&aaA[o + 4 * q];
                f.b[q] = *(const float4*)&b2A[o + 4 * q];
                f.k[q] = *(const float4*)&kA[o + 4 * q];
                f.r[q] = *(const float4*)&rA[o + 4 * q];
            }
            f.vv = vA[base + t * CC + row];
        };

        auto stepf = [&](const WFrag& f, int t) {
            const float vv = f.vv;
            float vk[8];
#pragma unroll
            for (int q = 0; q < 2; ++q) {
                vk[4*q+0] = vv * f.k[q].x;
                vk[4*q+1] = vv * f.k[q].y;
                vk[4*q+2] = vv * f.k[q].z;
                vk[4*q+3] = vv * f.k[q].w;
            }

            float t0 = 0.f, t1 = 0.f, t2 = 0.f, t3 = 0.f;
#pragma unroll
            for (int q = 0; q < 2; ++q) {
                float4 a4 = f.a[q];
                t0 = fmaf(S[4*q+0], a4.x, t0);
                t1 = fmaf(S[4*q+1], a4.y, t1);
                t2 = fmaf(S[4*q+2], a4.z, t2);
                t3 = fmaf(S[4*q+3], a4.w, t3);
            }
            float part = (t0 + t1) + (t2 + t3);
            float s08 = __shfl_xor(part,  8, 64);
            float s16 = __shfl_xor(part, 16, 64);
            float s24 = __shfl_xor(part, 24, 64);
            float s32 = __shfl_xor(part, 32, 64);
            float s40 = __shfl_xor(part, 40, 64);
            float s48 = __shfl_xor(part, 48, 64);
            float s56 = __shfl_xor(part, 56, 64);
            float tmp = ((part + s08) + (s16 + s24)) + ((s32 + s40) + (s48 + s56));

            float y0 = 0.f, y1 = 0.f, y2 = 0.f, y3 = 0.f;
#pragma unroll
            for (int q = 0; q < 2; ++q) {
                float4 w4 = f.w[q], b4 = f.b[q], r4 = f.r[q];
                S[4*q+0] = fmaf(S[4*q+0], w4.x, fmaf(tmp, b4.x, vk[4*q+0]));
                y0 = fmaf(S[4*q+0], r4.x, y0);
                S[4*q+1] = fmaf(S[4*q+1], w4.y, fmaf(tmp, b4.y, vk[4*q+1]));
                y1 = fmaf(S[4*q+1], r4.y, y1);
                S[4*q+2] = fmaf(S[4*q+2], w4.z, fmaf(tmp, b4.z, vk[4*q+2]));
                y2 = fmaf(S[4*q+2], r4.z, y2);
                S[4*q+3] = fmaf(S[4*q+3], w4.w, fmaf(tmp, b4.w, vk[4*q+3]));
                y3 = fmaf(S[4*q+3], r4.w, y3);
            }
            // no cross-lane y reduction: store this lane's bf16 partial
            yp8[ybase + t * CC] = f2bf((y0 + y1) + (y2 + y3));
        };

        loadfrag(f0, 0);
        loadfrag(f1, 1);
        loadfrag(f2, 2);

        int t = 0;
        for (; t + 2 < TT; t += 3) {
            stepf(f0, t);
            if (t + 3 < TT) loadfrag(f0, t + 3);
            stepf(f1, t + 1);
            if (t + 4 < TT) loadfrag(f1, t + 4);
            stepf(f2, t + 2);
            if (t + 5 < TT) loadfrag(f2, t + 5);
        }
        if (t < TT) stepf(f0, t);
        if (t + 1 < TT) stepf(f1, t + 1);
        return;
    }

    // ---------------- gate lora-out GEMM path ----------------
    // gbuf_b(t,c) = sum_k gw2[c][k] * ghh_b[k][t]   (K=192, TOUT epilogue)
    {
        const int gb = blockIdx.x - 192;       // 0..767
        const int n0t = (gb & 31) * 64;        // T tile
        const int rest = gb >> 5;              // 0..23
        const int m0t = (rest % 12) * 64;      // C tile (768/64)
        const int bz  = rest / 12;             // batch
        const float* A  = gw2;                           // (768 x 192)
        const float* Bm = ghh + (size_t)bz * (192L * TT);
        float* Cm = gbuf + (size_t)bz * ((long)TT * CC);
        const int tid = threadIdx.x;

        __shared__ float As[16][64];
        __shared__ float Bs[16][64];

        const int mi = (tid & 15) * 4, ni = (tid >> 4) * 4;  // TOUT layout
        float acc[4][4];
#pragma unroll
        for (int i = 0; i < 4; ++i)
#pragma unroll
            for (int j = 0; j < 4; ++j) acc[i][j] = 0.f;

        for (int k0 = 0; k0 < 192; k0 += 16) {
            {
                const int row = tid >> 2, kc = (tid & 3) * 4;
                float4 av = *(const float4*)&A[(size_t)(m0t + row) * 192 + k0 + kc];
                As[kc + 0][row] = av.x; As[kc + 1][row] = av.y;
                As[kc + 2][row] = av.z; As[kc + 3][row] = av.w;
            }
            {
                const int krow = tid >> 4, tc = (tid & 15) * 4;
                *(float4*)&Bs[krow][tc] = *(const float4*)&Bm[(size_t)(k0 + krow) * TT + n0t + tc];
            }
            __syncthreads();
#pragma unroll
            for (int kk = 0; kk < 16; ++kk) {
                float4 a4 = *(const float4*)&As[kk][mi];
                float4 b4 = *(const float4*)&Bs[kk][ni];
                float am[4] = {a4.x, a4.y, a4.z, a4.w};
                float bn[4] = {b4.x, b4.y, b4.z, b4.w};
#pragma unroll
                for (int i = 0; i < 4; ++i)
#pragma unroll
                    for (int j = 0; j < 4; ++j) acc[i][j] = fmaf(am[i], bn[j], acc[i][j]);
            }
            __syncthreads();
        }
        const int mbase = m0t + mi, nbase = n0t + ni;
#pragma unroll
        for (int j = 0; j < 4; ++j) {
            float4 o = {acc[0][j], acc[1][j], acc[2][j], acc[3][j]};
            *(float4*)&Cm[(size_t)(nbase + j) * CC + mbase] = o;
        }
    }
}

// ---------------------------------------------------------------------------
// E2: sum 8 bf16 y-partials, RMSNorm*lnw + (sum_head r*k*faaaa)*v, *g -> bf16 z
// ---------------------------------------------------------------------------
__global__ __launch_bounds__(256) void e2_kernel(
    const unsigned short* __restrict__ yp8, const float* __restrict__ rA,
    const float* __restrict__ kA, const float* __restrict__ vA,
    const float* __restrict__ gA, const float* __restrict__ faaaa,
    const float* __restrict__ lnw, unsigned short* __restrict__ zB)
{
    const int bt = blockIdx.x;
    const int b = bt / TT, t = bt - b * TT;
    const size_t base = (size_t)bt * CC;
    const int tid = threadIdx.x;
    const int wave = tid >> 6;
    __shared__ float red[4];
    __shared__ float rk[12];

    float yv[3];
    float ss = 0.f;
#pragma unroll
    for (int ch = 0; ch < 3; ++ch) {
        int c = ch * 256 + tid;
        float y = 0.f;
#pragma unroll
        for (int jg = 0; jg < 8; ++jg)
            y += bf2f(yp8[((size_t)(jg * BB + b) * TT + t) * CC + c]);
        yv[ch] = y;
        ss = fmaf(y, y, ss);
        float p = rA[base + c] * kA[base + c] * faaaa[c];
#pragma unroll
        for (int off = 32; off; off >>= 1) p += __shfl_xor(p, off, 64);
        if ((tid & 63) == 0) rk[ch * 4 + wave] = p;
    }
#pragma unroll
    for (int off = 32; off; off >>= 1) ss += __shfl_xor(ss, off, 64);
    if ((tid & 63) == 0) red[wave] = ss;
    __syncthreads();
    const float total = red[0] + red[1] + red[2] + red[3];
    const float scale = rsqrtf(total / (float)CC + 1e-5f);
#pragma unroll
    for (int ch = 0; ch < 3; ++ch) {
        int c = ch * 256 + tid;
        float out = yv[ch] * scale * lnw[c] + rk[c >> 6] * vA[base + c];
        zB[base + c] = f2bf(out * gA[base + c]);
    }
}

// ---------------------------------------------------------------------------
extern "C" void kernel_launch(void* const* d_in, const int* in_sizes, int n_in,
                              void* d_out, int out_size, void* d_ws, size_t ws_size,
                              hipStream_t stream)
{
    (void)in_sizes; (void)n_in; (void)out_size; (void)ws_size;
    const float* x        = (const float*)d_in[0];
    const float* tmaa_r   = (const float*)d_in[2];
    const float* tmaa_w   = (const float*)d_in[3];
    const float* tmaa_k   = (const float*)d_in[4];
    const float* tmaa_v   = (const float*)d_in[5];
    const float* tmaa_a   = (const float*)d_in[6];
    const float* tmaa_g   = (const float*)d_in[7];
    const float* tdecay   = (const float*)d_in[8];
    const float* tfaaaa   = (const float*)d_in[9];
    const float* taaaaa   = (const float*)d_in[10];
    const float* maa_w1   = (const float*)d_in[11];
    const float* maa_w2   = (const float*)d_in[12];
    const float* decay_w1 = (const float*)d_in[13];
    const float* decay_w2 = (const float*)d_in[14];
    const float* aaa_w1   = (const float*)d_in[15];
    const float* aaa_w2   = (const float*)d_in[16];
    const float* kkk_w1   = (const float*)d_in[17];
    const float* kkk_w2   = (const float*)d_in[18];
    const float* gate_w1  = (const float*)d_in[19];
    const float* gate_w2  = (const float*)d_in[20];
    const float* w_key    = (const float*)d_in[21];
    const float* w_value  = (const float*)d_in[22];
    const float* w_recept = (const float*)d_in[23];
    const float* w_output = (const float*)d_in[24];
    const float* lnw      = (const float*)d_in[25];
    float* out = (float*)d_out;

    float* ws   = (float*)d_ws;
    float* paux = ws;                 // 6*768
    float* tm   = ws + 8192;          // S1
    float* X6   = tm + S1;            // 6*FF
    float* dh   = X6 + 6 * FF;        // B*64*T = 262144
    float* ah   = dh + 262144;
    float* kh   = ah + 262144;
    float* gh   = kh + 262144;        // B*192*T = 786432
    float* gbuf = gh + 786432;        // FF
    // bf16 region
    unsigned short* yp8 = (unsigned short*)(gbuf + FF);  // 8*FF  (y partials)
    unsigned short* X6b = yp8 + 8 * FF;                  // 3*FF  (xr,xk,xv bf16 (C,T))
    unsigned short* zb  = X6b + 3 * FF;                  // FF
    unsigned short* wb  = zb + FF;                       // 5*294912
    unsigned short* xtb = wb + 5L * 294912;              // FF    (x bf16 (T,C))
    unsigned short* X6t = xtb + FF;                      // 3*FF  (xr,xk,xv bf16 (T,C))

    float* xw = X6 + 1 * FF; float* xk = X6 + 2 * FF;
    float* xa = X6 + 4 * FF; float* xg = X6 + 5 * FF;
    float* wwB = X6 + 0 * FF; float* rB  = X6 + 1 * FF; float* aaB = X6 + 2 * FF;
    float* b2B = X6 + 3 * FF; float* kB  = X6 + 4 * FF; float* vB  = X6 + 5 * FF;

    const long CT = (long)CC * TT;        // 1572864
    const long TC = (long)TT * CC;        // 1572864

    // wcvt + xtr + pack_aux merged into one launch
    wcvt_kernel<<<dim3(6529), 256, 0, stream>>>(
        w_recept, w_key, w_value, w_output, maa_w1, wb,
        tmaa_r, tmaa_w, tmaa_k, tmaa_v, tmaa_a, tmaa_g, paux,
        x, xtb);

    // tm = tanh(maa_w1 @ x)  via bf16 MFMA
    maaw1_mfma_kernel<<<dim3(16, 3, 2), 256, 0, stream>>>(wb + 4L * 294912, xtb, tm);

    // X6[n] = x * (paux[n] + maa_w2[n]^T @ tm_n); bf16 side-write r/k/v;
    // fp32 store skipped for slots 0,3 (never read as fp32)
    gemm_kernel<1,0,0,2><<<dim3(32, 12, 12), 256, 0, stream>>>(
        maa_w2, tm, X6, paux, x,
        64, 768, TT, TT, 6,
        0, 64L * 768, 384L * TT, 64L * TT, CT, FF, 768, CT, X6b);

    // transpose bf16 conv inputs (C,T) -> (T,C)
    btr_kernel<<<dim3(32, 12, 6), 256, 0, stream>>>(X6b, X6t);

    // merged lora hiddens (decay/aaa/kkk/gate _w1, tanh)
    lorah_kernel<<<dim3(32, 3, 8), 256, 0, stream>>>(
        decay_w1, aaa_w1, kkk_w1, gate_w1, xw, xa, xk, xg, dh, ah, kh, gh);

    // merged 3 input convs via bf16 MFMA -> rB/kB/vB (fp32 (B,T,C))
    convs3_mfma_kernel<<<dim3(16, 3, 12), 256, 0, stream>>>(wb, X6t, X6);

    // merged lora-outs (decay/aaa/kkk) -> (B,T,C); gate GEMM lives in wkv launch
    loraout_kernel<<<dim3(32, 12, 6), 256, 0, stream>>>(
        decay_w2, aaa_w2, kkk_w2, dh, ah, kh, tdecay, taaaaa, wwB, b2B, aaB);

    // E1: build aa (over kvec slot) and b2 (over a slot)
    e1_kernel<<<dim3(BB * TT), 256, 0, stream>>>(kB, aaB, b2B);

    // WKV v17: exact v11 recurrence + gate GEMM fused into the same launch
    wkv_gate_kernel<<<dim3(960), 256, 0, stream>>>(
        rB, wwB, kB, vB, aaB, b2B, yp8, gate_w2, gh, gbuf);

    // E2: sum partials + rmsnorm + faaaa bonus + gate -> bf16 z
    e2_kernel<<<dim3(BB * TT), 256, 0, stream>>>(yp8, rB, kB, vB, gbuf, tfaaaa, lnw, zb);

    // final grouped conv via bf16 MFMA: z (B,T,C) -> out (B,C,T)
    convout_mfma_kernel<<<dim3(16, 3, 4), 256, 0, stream>>>(wb + 3L * 294912, zb, out);
}